// Round 12
// baseline (156.709 us; speedup 1.0000x reference)
//
#include <hip/hip_runtime.h>
#include <hip/hip_bf16.h>

// FocusAttention: B=8, L=S=1024, H=8, E=D=64
// A = softmax(c * s^2) rowwise, c = sqrt(sum s^2 / sum s^4) (full-row const
// -> two passes over K; recompute QK^T in pass 2). out = A @ v, fp32.
//
// R18: R17 banked (attn 41.7, total 143.7; pass-1 C=2 chunking worth
// ~0.5us/barrier). Retro-diagnosis: R15's 63us poison was most likely
// setprio in barrier-locked 8-wave blocks (m190's negative regime) -- the
// VGPR-cliff theory was wrong (72 VGPR still allows 7 waves/SIMD); union
// overlay (R12) and stats side-buffer (R15) are correctness-verified and
// likely innocent.
// Delta: pass-2 C=2 chunking -- second staging slot pair x_t/y_t for odd
// tiles (even -> k/v[p], odd -> x/y[p]); pass-2 barriers 16 -> 8, same WAR
// pattern as R17's pass-1. To stay at 2 blocks/CU, final merge OVERLAYS the
// dead staging via typed union (R12-verified) and stats merge moves to a
// 3KB side buffer (R15-verified): LDS 68.6KB.
// Kept: R17 pass-1 C=2, MFMA denominator, swapped-operand QK^T, in-register
// w->A-frag (cvt_pkrtz+permlane), fp16, XCD swizzle, Q/K/V XOR swizzles,
// glds double-buffer, raw v_exp_f32, NO setprio, launch_bounds(512,4).

#define B_ 8
#define L_ 1024
#define H_ 8
#define E_ 64
#define S_ 1024
#define D_ 64
#define BH_ 64

typedef _Float16 f16_t;
typedef _Float16 f16x8 __attribute__((ext_vector_type(8)));
typedef float f32x4 __attribute__((ext_vector_type(4)));
typedef unsigned u32x4 __attribute__((ext_vector_type(4)));

#define MFMA16F(a, b, c) __builtin_amdgcn_mfma_f32_16x16x32_f16(a, b, c, 0, 0, 0)
#define GLDS16(g, l)                                                        \
  __builtin_amdgcn_global_load_lds(                                         \
      (const __attribute__((address_space(1))) void*)(g),                   \
      (__attribute__((address_space(3))) void*)(l), 16, 0, 0)

#if __has_builtin(__builtin_amdgcn_exp2f)
#define EXP2(x) __builtin_amdgcn_exp2f(x)
#else
#define EXP2(x) exp2f(x)
#endif

// pack 2 f32 -> 1 dword of 2 f16 (v_cvt_pkrtz_f16_f32)
static __device__ __forceinline__ unsigned pkh(float a, float b) {
  return __builtin_bit_cast(unsigned, __builtin_amdgcn_cvt_pkrtz(a, b));
}

// v_permlane32_swap_b32: x[32:63] <-> y[0:31].
static __device__ __forceinline__ void pl32_swap(unsigned& x, unsigned& y) {
#if __has_builtin(__builtin_amdgcn_permlane32_swap)
  auto r = __builtin_amdgcn_permlane32_swap(x, y, false, false);
  x = r[0];
  y = r[1];
#else
  unsigned xs = __shfl_xor((int)x, 32, 64), ys = __shfl_xor((int)y, 32, 64);
  bool hi = (threadIdx.x & 32) != 0;
  unsigned nx = hi ? ys : x;
  unsigned ny = hi ? y : xs;
  x = nx;
  y = ny;
#endif
}

// v_permlane16_swap_b32: x rows {1,3} <-> y rows {0,2} (16-lane rows).
static __device__ __forceinline__ void pl16_swap(unsigned& x, unsigned& y) {
#if __has_builtin(__builtin_amdgcn_permlane16_swap)
  auto r = __builtin_amdgcn_permlane16_swap(x, y, false, false);
  x = r[0];
  y = r[1];
#else
  unsigned xs = __shfl_xor((int)x, 16, 64), ys = __shfl_xor((int)y, 16, 64);
  bool odd = (threadIdx.x & 16) != 0;
  unsigned nx = odd ? ys : x;
  unsigned ny = odd ? y : xs;
  x = nx;
  y = ny;
#endif
}

// ---------------------------------------------------------------------------
// prep (R15-verified): blocks [0,4096) = phi_p on q,k rows (8 threads/row,
// 32 rows/block, float4 x2 loads, full f16x8 swizzled stores);
// blocks [4096,6144) = V transpose to vt[bh][st=S/32][64 d][32 s] f16,
// s-chunk XOR-swizzled by (d>>1)&3.
// Q/K XOR chunk swizzle: chunk c of row l stored at chunk c^(l&7).
// ---------------------------------------------------------------------------
__global__ __launch_bounds__(256) void prep_kernel(
    const float* __restrict__ q, const float* __restrict__ k,
    const float* __restrict__ v, f16_t* __restrict__ qf,
    f16_t* __restrict__ kf, f16_t* __restrict__ vt) {
  __shared__ float tile[32][68];
  int bid = blockIdx.x;
  if (bid < 4096) {
    int row = bid * 32 + (threadIdx.x >> 3);
    int p = threadIdx.x & 7;  // chunk index (8 elems)
    const float* src;
    f16_t* dst;
    int r = row;
    if (r < B_ * L_ * H_) { src = q; dst = qf; }
    else { r -= B_ * L_ * H_; src = k; dst = kf; }
    int b = r >> 13;            // r / (L*H)
    int l = (r >> 3) & 1023;
    int h = r & 7;
    const float4* sp = (const float4*)(src + (size_t)r * 64) + p * 2;
    float4 x0 = sp[0];
    float4 x1 = sp[1];
    float s[8];
    s[0] = fmaxf(x0.x, 0.f) * fmaxf(x0.x, 0.f);
    s[1] = fmaxf(x0.y, 0.f) * fmaxf(x0.y, 0.f);
    s[2] = fmaxf(x0.z, 0.f) * fmaxf(x0.z, 0.f);
    s[3] = fmaxf(x0.w, 0.f) * fmaxf(x0.w, 0.f);
    s[4] = fmaxf(x1.x, 0.f) * fmaxf(x1.x, 0.f);
    s[5] = fmaxf(x1.y, 0.f) * fmaxf(x1.y, 0.f);
    s[6] = fmaxf(x1.z, 0.f) * fmaxf(x1.z, 0.f);
    s[7] = fmaxf(x1.w, 0.f) * fmaxf(x1.w, 0.f);
    float sum2 = ((s[0] + s[1]) + (s[2] + s[3])) +
                 ((s[4] + s[5]) + (s[6] + s[7]));
    float sum4 = (fmaf(s[0], s[0], s[1] * s[1]) + fmaf(s[2], s[2], s[3] * s[3])) +
                 (fmaf(s[4], s[4], s[5] * s[5]) + fmaf(s[6], s[6], s[7] * s[7]));
#pragma unroll
    for (int off = 1; off < 8; off <<= 1) {
      sum2 += __shfl_xor(sum2, off, 64);
      sum4 += __shfl_xor(sum4, off, 64);
    }
    float sc = (sum4 > 0.f) ? sqrtf(sum2 / sum4) : 0.f;
    f16x8 o;
#pragma unroll
    for (int j = 0; j < 8; ++j) o[j] = (f16_t)(sc * s[j]);
    int col = (p ^ (l & 7)) << 3;
    *(f16x8*)(dst + ((size_t)(b * H_ + h) * 1024 + l) * 64 + col) = o;
  } else {
    int vb = bid - 4096;
    int bh = vb >> 5;
    int st = vb & 31;
    int b = bh >> 3, h = bh & 7;
    int t = threadIdx.x;
    int sl = t >> 3, dp = t & 7;
    const float* src =
        v + (((size_t)(b * S_ + st * 32 + sl) * H_ + h) * D_) + dp * 8;
    float4 f0 = ((const float4*)src)[0];
    float4 f1 = ((const float4*)src)[1];
    *(float4*)&tile[sl][dp * 8] = f0;
    *(float4*)&tile[sl][dp * 8 + 4] = f1;
    __syncthreads();
    int d = t >> 2, sc = t & 3;
    f16_t tmp[8];
#pragma unroll
    for (int j = 0; j < 8; ++j) tmp[j] = (f16_t)tile[sc * 8 + j][d];
    // s-chunk XOR swizzle by (d>>1)&3 -> conflict-free attn V reads
    f16_t* dst =
        vt + (((size_t)bh * 32 + st) * 64 + d) * 32 + (sc ^ ((d >> 1) & 3)) * 8;
    *(uint4*)dst = *(const uint4*)tmp;
  }
}

// ---------------------------------------------------------------------------
// K2 (R17 chassis + pass-2 C=2 chunking):
// Block = (b,h) x 128 q-rows, 512 threads = 8 waves. wave = (sh, wv):
// sh = s-half (tiles sh*16..sh*16+15), wv = row group (rows wv*32 + two
// 16-row sets). 16 waves/CU (grid 512, 2 blocks/CU).
// SWAPPED score MFMA: S^T = mfma(K_frag, Q_frag); lane(g,n) holds scores for
// q-row n. PV A-frag assembled in-register (cvt_pkrtz + permlane swaps).
// den_row = mfma(wa, ones): D[m=4g+r] = Sum_s w in per-row layout.
// BOTH passes stage in 2-tile chunks (8 barriers each): pass 1 uses v_t as
// the odd-K slot; pass 2 uses x_t/y_t as the odd-(K,V) slots.
// Final merge overlays the dead staging (typed union); stats merge via 3KB
// side buffer. No setprio (hurts barrier-locked blocks, m190/R15).
// ---------------------------------------------------------------------------
struct Stage {
  f16_t k[2][2][2048];  // [shalf][dbuf] even-tile K (pass1: even K too)
  f16_t v[2][2][2048];  // [shalf][dbuf] even-tile V (pass1: odd-K slot)
  f16_t x[2][2][2048];  // [shalf][dbuf] pass-2 odd-tile K
  f16_t y[2][2][2048];  // [shalf][dbuf] pass-2 odd-tile V
};
union SMemOverlay {
  Stage s;               // 64 KB, live during passes
  float mrg[4][64][40];  // 40 KB, live during final merge (staging dead)
};

__global__ __launch_bounds__(512, 4) void attn_kernel(
    const f16_t* __restrict__ qf, const f16_t* __restrict__ kf,
    const f16_t* __restrict__ vt, float* __restrict__ out) {
  __shared__ __align__(16) SMemOverlay sm;
  __shared__ float stats[8 * 16 * 6];  // 3KB side buffer (mid-kernel merge)

  int bh = blockIdx.x & 63;   // XCD swizzle: all q-blocks of a head co-located
  int qb = blockIdx.x >> 6;   // 0..3 (128 rows each)
  int b = bh >> 3, h = bh & 7;
  int tid = threadIdx.x;
  int wave = tid >> 6, lane = tid & 63;
  int wv = wave & 3, sh = wave >> 2;
  int g = lane >> 4, n = lane & 15;

  const f16_t* qf_b = qf + ((size_t)bh * L_ + qb * 128) * 64;
  const f16_t* kf_b = kf + (size_t)bh * S_ * 64 + (size_t)sh * 16 * 2048;
  const f16_t* vt_b = vt + (size_t)bh * 32 * 2048 + (size_t)sh * 16 * 2048;

  // Q fragments, two sets (swizzled chunk addressing)
  int arow = wv * 32 + n;
  int qoff0 = arow * 64 + ((g ^ (n & 7)) << 3);
  int qoff1 = qoff0 + 16 * 64;
  f16x8 qa0_0 = *(const f16x8*)(qf_b + qoff0);
  f16x8 qa1_0 = *(const f16x8*)(qf_b + (qoff0 ^ 32));
  f16x8 qa0_1 = *(const f16x8*)(qf_b + qoff1);
  f16x8 qa1_1 = *(const f16x8*)(qf_b + (qoff1 ^ 32));

  // K fragment offset (row n; row n+16 at +1024); V frag offset (swizzled)
  int koff = n * 64 + ((g ^ (n & 7)) << 3);
  int voff = n * 32 + ((g ^ ((n >> 1) & 3)) << 3);
  int so = (tid & 255) * 8;  // lane-linear glds staging slot in own half

  const f32x4 fzero = {0.f, 0.f, 0.f, 0.f};
  f32x4 acc2_0 = fzero, acc4_0 = fzero, mx_0 = fzero;
  f32x4 acc2_1 = fzero, acc4_1 = fzero, mx_1 = fzero;

// one pass-1 tile: stats accumulate from K tile at LDS pointer KT
#define P1_TILE(KT)                                                          \
  {                                                                          \
    const f16_t* kt = (KT);                                                  \
    f16x8 b00 = *(const f16x8*)(kt + koff);                                  \
    f16x8 b01 = *(const f16x8*)(kt + (koff ^ 32));                           \
    f16x8 b10 = *(const f16x8*)(kt + koff + 1024);                           \
    f16x8 b11 = *(const f16x8*)(kt + (koff ^ 32) + 1024);                    \
    f32x4 sc0_0 = MFMA16F(b00, qa0_0, fzero);                                \
    sc0_0 = MFMA16F(b01, qa1_0, sc0_0);                                      \
    f32x4 sc1_0 = MFMA16F(b10, qa0_0, fzero);                                \
    sc1_0 = MFMA16F(b11, qa1_0, sc1_0);                                      \
    f32x4 sc0_1 = MFMA16F(b00, qa0_1, fzero);                                \
    sc0_1 = MFMA16F(b01, qa1_1, sc0_1);                                      \
    f32x4 sc1_1 = MFMA16F(b10, qa0_1, fzero);                                \
    sc1_1 = MFMA16F(b11, qa1_1, sc1_1);                                      \
    f32x4 t0 = sc0_0 * sc0_0, t1 = sc1_0 * sc1_0;                            \
    acc2_0 += t0 + t1;                                                       \
    acc4_0 += t0 * t0;                                                       \
    acc4_0 += t1 * t1;                                                       \
    mx_0 = __builtin_elementwise_max(mx_0, __builtin_elementwise_max(t0, t1)); \
    f32x4 u0 = sc0_1 * sc0_1, u1 = sc1_1 * sc1_1;                            \
    acc2_1 += u0 + u1;                                                       \
    acc4_1 += u0 * u0;                                                       \
    acc4_1 += u1 * u1;                                                       \
    mx_1 = __builtin_elementwise_max(mx_1, __builtin_elementwise_max(u0, u1)); \
  }

  // ---- PASS 1 (own s-half): K in 2-tile chunks (v_t = odd-tile slot) ----
  GLDS16(kf_b + so, &sm.s.k[sh][0][so]);          // tile 0
  GLDS16(kf_b + 2048 + so, &sm.s.v[sh][0][so]);   // tile 1
  for (int c = 0; c < 8; ++c) {
    __syncthreads();  // drains glds -> chunk c ready (both halves)
    if (c < 7) {
      int go = (2 * c + 2) * 2048 + so;
      int bs = (c + 1) & 1;
      GLDS16(kf_b + go, &sm.s.k[sh][bs][so]);         // tile 2c+2
      GLDS16(kf_b + go + 2048, &sm.s.v[sh][bs][so]);  // tile 2c+3
    }
    P1_TILE(sm.s.k[sh][c & 1]);  // tile 2c
    P1_TILE(sm.s.v[sh][c & 1]);  // tile 2c+1
  }
#undef P1_TILE
  // kick off pass-2 chunk-0 staging (k/v bufs: last pass-1 read was chunk 6,
  // ordered by chunk-7 barrier; x/y: untouched in pass 1). Overlaps merge.
  GLDS16(kf_b + so, &sm.s.k[sh][0][so]);
  GLDS16(vt_b + so, &sm.s.v[sh][0][so]);
  GLDS16(kf_b + 2048 + so, &sm.s.x[sh][0][so]);
  GLDS16(vt_b + 2048 + so, &sm.s.y[sh][0][so]);

  // in-wave reduce -> per-lane partial scalars (replicated over g)
  float a2_0 = (acc2_0[0] + acc2_0[1]) + (acc2_0[2] + acc2_0[3]);
  float a4_0 = (acc4_0[0] + acc4_0[1]) + (acc4_0[2] + acc4_0[3]);
  float m2_0 = fmaxf(fmaxf(mx_0[0], mx_0[1]), fmaxf(mx_0[2], mx_0[3]));
  float a2_1 = (acc2_1[0] + acc2_1[1]) + (acc2_1[2] + acc2_1[3]);
  float a4_1 = (acc4_1[0] + acc4_1[1]) + (acc4_1[2] + acc4_1[3]);
  float m2_1 = fmaxf(fmaxf(mx_1[0], mx_1[1]), fmaxf(mx_1[2], mx_1[3]));
  a2_0 += __shfl_xor(a2_0, 16, 64);
  a4_0 += __shfl_xor(a4_0, 16, 64);
  m2_0 = fmaxf(m2_0, __shfl_xor(m2_0, 16, 64));
  a2_1 += __shfl_xor(a2_1, 16, 64);
  a4_1 += __shfl_xor(a4_1, 16, 64);
  m2_1 = fmaxf(m2_1, __shfl_xor(m2_1, 16, 64));
  a2_0 += __shfl_xor(a2_0, 32, 64);
  a4_0 += __shfl_xor(a4_0, 32, 64);
  m2_0 = fmaxf(m2_0, __shfl_xor(m2_0, 32, 64));
  a2_1 += __shfl_xor(a2_1, 32, 64);
  a4_1 += __shfl_xor(a4_1, 32, 64);
  m2_1 = fmaxf(m2_1, __shfl_xor(m2_1, 32, 64));

  // cross-half stats merge via 3KB side buffer (n-replicated: g==0 writes).
  // Fixed-order sum over halves -> identical c2 in all waves.
  if (g == 0) {
    float* sp = stats + ((size_t)(wave * 16 + n)) * 6;
    sp[0] = a2_0; sp[1] = a4_0; sp[2] = m2_0;
    sp[3] = a2_1; sp[4] = a4_1; sp[5] = m2_1;
  }
  __syncthreads();
  float A2_0 = 0.f, A4_0 = 0.f, M2_0 = 0.f;
  float A2_1 = 0.f, A4_1 = 0.f, M2_1 = 0.f;
#pragma unroll
  for (int qq = 0; qq < 2; ++qq) {
    const float* sp = stats + ((size_t)((qq * 4 + wv) * 16 + n)) * 6;
    A2_0 += sp[0]; A4_0 += sp[1]; M2_0 = fmaxf(M2_0, sp[2]);
    A2_1 += sp[3]; A4_1 += sp[4]; M2_1 = fmaxf(M2_1, sp[5]);
  }
  const float LOG2E = 1.44269504f;
  float c2_0 = (A4_0 > 0.f) ? (sqrtf(A2_0 / A4_0) * LOG2E) : 0.f;
  float cm2_0 = c2_0 * M2_0;
  float c2_1 = (A4_1 > 0.f) ? (sqrtf(A2_1 / A4_1) * LOG2E) : 0.f;
  float cm2_1 = c2_1 * M2_1;

  // ---- PASS 2 (own s-half): scores -> w -> partial PV; 2-tile chunks ----
  f32x4 pv0[4], pv1[4];
#pragma unroll
  for (int dg = 0; dg < 4; ++dg) { pv0[dg] = fzero; pv1[dg] = fzero; }
  f32x4 dacc0 = fzero, dacc1 = fzero;  // den rows via MFMA(wa, ones)
  const f16x8 vone = {(f16_t)1, (f16_t)1, (f16_t)1, (f16_t)1,
                      (f16_t)1, (f16_t)1, (f16_t)1, (f16_t)1};

// one pass-2 tile from K tile KT / V tile VL
#define P2_TILE(KT, VL)                                                      \
  {                                                                          \
    const f16_t* kt = (KT);                                                  \
    const f16_t* vl = (VL);                                                  \
    f16x8 vb[4];                                                             \
    _Pragma("unroll") for (int dg = 0; dg < 4; ++dg)                         \
        vb[dg] = *(const f16x8*)(vl + voff + dg * 512);                      \
    f16x8 b00 = *(const f16x8*)(kt + koff);                                  \
    f16x8 b01 = *(const f16x8*)(kt + (koff ^ 32));                           \
    f16x8 b10 = *(const f16x8*)(kt + koff + 1024);                           \
    f16x8 b11 = *(const f16x8*)(kt + (koff ^ 32) + 1024);                    \
    f32x4 sc0_0 = MFMA16F(b00, qa0_0, fzero);                                \
    sc0_0 = MFMA16F(b01, qa1_0, sc0_0);                                      \
    f32x4 sc1_0 = MFMA16F(b10, qa0_0, fzero);                                \
    sc1_0 = MFMA16F(b11, qa1_0, sc1_0);                                      \
    f32x4 sc0_1 = MFMA16F(b00, qa0_1, fzero);                                \
    sc0_1 = MFMA16F(b01, qa1_1, sc0_1);                                      \
    f32x4 sc1_1 = MFMA16F(b10, qa0_1, fzero);                                \
    sc1_1 = MFMA16F(b11, qa1_1, sc1_1);                                      \
    f32x4 e0 = sc0_0 * sc0_0 * c2_0 - cm2_0;                                 \
    f32x4 e1 = sc1_0 * sc1_0 * c2_0 - cm2_0;                                 \
    f32x4 w0, w1;                                                            \
    _Pragma("unroll") for (int r = 0; r < 4; ++r) {                          \
      w0[r] = EXP2(e0[r]);                                                   \
      w1[r] = EXP2(e1[r]);                                                   \
    }                                                                        \
    unsigned X0 = pkh(w0[0], w0[1]), X1 = pkh(w0[2], w0[3]);                 \
    unsigned Y0 = pkh(w1[0], w1[1]), Y1 = pkh(w1[2], w1[3]);                 \
    pl32_swap(X0, Y0);                                                       \
    pl16_swap(X0, Y0);                                                       \
    pl32_swap(X1, Y1);                                                       \
    pl16_swap(X1, Y1);                                                       \
    u32x4 fu0 = {X0, X1, Y0, Y1};                                            \
    f16x8 wa0 = __builtin_bit_cast(f16x8, fu0);                              \
    f32x4 f0v = sc0_1 * sc0_1 * c2_1 - cm2_1;                                \
    f32x4 f1v = sc1_1 * sc1_1 * c2_1 - cm2_1;                                \
    f32x4 z0, z1;                                                            \
    _Pragma("unroll") for (int r = 0; r < 4; ++r) {                          \
      z0[r] = EXP2(f0v[r]);                                                  \
      z1[r] = EXP2(f1v[r]);                                                  \
    }                                                                        \
    unsigned P0 = pkh(z0[0], z0[1]), P1 = pkh(z0[2], z0[3]);                 \
    unsigned Q0 = pkh(z1[0], z1[1]), Q1 = pkh(z1[2], z1[3]);                 \
    pl32_swap(P0, Q0);                                                       \
    pl16_swap(P0, Q0);                                                       \
    pl32_swap(P1, Q1);                                                       \
    pl16_swap(P1, Q1);                                                       \
    u32x4 fu1 = {P0, P1, Q0, Q1};                                            \
    f16x8 wa1 = __builtin_bit_cast(f16x8, fu1);                              \
    dacc0 = MFMA16F(wa0, vone, dacc0);                                       \
    dacc1 = MFMA16F(wa1, vone, dacc1);                                       \
    _Pragma("unroll") for (int dg = 0; dg < 4; ++dg) {                       \
      pv0[dg] = MFMA16F(wa0, vb[dg], pv0[dg]);                               \
      pv1[dg] = MFMA16F(wa1, vb[dg], pv1[dg]);                               \
    }                                                                        \
  }

  for (int c = 0; c < 8; ++c) {
    __syncthreads();  // drains glds -> chunk c (tiles 2c,2c+1) ready
    if (c < 7) {
      int go = (2 * c + 2) * 2048 + so;
      int bs = (c + 1) & 1;
      GLDS16(kf_b + go, &sm.s.k[sh][bs][so]);         // tile 2c+2 K
      GLDS16(vt_b + go, &sm.s.v[sh][bs][so]);         // tile 2c+2 V
      GLDS16(kf_b + go + 2048, &sm.s.x[sh][bs][so]);  // tile 2c+3 K
      GLDS16(vt_b + go + 2048, &sm.s.y[sh][bs][so]);  // tile 2c+3 V
    }
    P2_TILE(sm.s.k[sh][c & 1], sm.s.v[sh][c & 1]);  // tile 2c
    P2_TILE(sm.s.x[sh][c & 1], sm.s.y[sh][c & 1]);  // tile 2c+1
  }
#undef P2_TILE

  // ---- cross-shalf pv/den merge overlaying the dead staging buffers ----
  __syncthreads();  // all staging reads complete
  if (sh == 1) {
    float* mp = &sm.mrg[wv][lane][0];
#pragma unroll
    for (int dg = 0; dg < 4; ++dg)
#pragma unroll
      for (int r = 0; r < 4; ++r) {
        mp[dg * 4 + r] = pv0[dg][r];
        mp[16 + dg * 4 + r] = pv1[dg][r];
      }
#pragma unroll
    for (int r = 0; r < 4; ++r) {
      mp[32 + r] = dacc0[r];
      mp[36 + r] = dacc1[r];
    }
  }
  __syncthreads();
  if (sh == 0) {
    const float* mp = &sm.mrg[wv][lane][0];
#pragma unroll
    for (int dg = 0; dg < 4; ++dg)
#pragma unroll
      for (int r = 0; r < 4; ++r) {
        pv0[dg][r] += mp[dg * 4 + r];
        pv1[dg][r] += mp[16 + dg * 4 + r];
      }
#pragma unroll
    for (int r = 0; r < 4; ++r) {
      dacc0[r] += mp[32 + r];
      dacc1[r] += mp[36 + r];
    }
#pragma unroll
    for (int r = 0; r < 4; ++r) {
      float inv0 = 1.f / dacc0[r];  // den for q-row 4g+r: already per-lane
      int l0 = qb * 128 + wv * 32 + g * 4 + r;
      float* op0 = out + (((size_t)b * L_ + l0) * H_ + h) * D_;
#pragma unroll
      for (int dg = 0; dg < 4; ++dg) op0[dg * 16 + n] = pv0[dg][r] * inv0;
      float inv1 = 1.f / dacc1[r];
      int l1 = l0 + 16;
      float* op1 = out + (((size_t)b * L_ + l1) * H_ + h) * D_;
#pragma unroll
      for (int dg = 0; dg < 4; ++dg) op1[dg * 16 + n] = pv1[dg][r] * inv1;
    }
  }
}

extern "C" void kernel_launch(void* const* d_in, const int* in_sizes, int n_in,
                              void* d_out, int out_size, void* d_ws, size_t ws_size,
                              hipStream_t stream) {
  const float* q = (const float*)d_in[0];
  const float* k = (const float*)d_in[1];
  const float* v = (const float*)d_in[2];
  // d_in[3] (attn_mask) is all-False -> unused
  float* out = (float*)d_out;

  const size_t NE = (size_t)B_ * L_ * H_ * E_;  // 4,194,304 elems
  f16_t* qf = (f16_t*)d_ws;                     // ws usage: 3*NE*2B = 24 MB
  f16_t* kf = qf + NE;
  f16_t* vt = kf + NE;

  prep_kernel<<<4096 + 2048, 256, 0, stream>>>(q, k, v, qf, kf, vt);
  attn_kernel<<<BH_ * (L_ / 128), 512, 0, stream>>>(qf, kf, vt, out);
}